// Round 14
// baseline (613.730 us; speedup 1.0000x reference)
//
#include <hip/hip_runtime.h>
#include <hip/hip_bf16.h>

// ---------------------------------------------------------------------------
// MiniTransformer: B=8,S=2048,D=1024,H=2048, fp32 in/out, bf16 MFMA inside.
// GEMM R14: occupancy push. 256x256 tile, BK=64, 2-dbuf LDS (128KB),
// *16 waves* (1024 thr, 4x4 wave grid, 64x64 wave tile), 16x16x32 MFMA
// (R13's 32x32 reverted: it reintroduced bank conflicts). acc[4][4]=64 AGPR
// + ~60 VGPR ~= 125 total -> 4 waves/SIMD (vs 2 all session at 22% occ).
// Phases/K-tile: ph1{read A(8)+B01(4) | stage A(u+1,0) | 16 MFMA}
//   ph2{read B23(4) | stage A(u+1,1) | 16 MFMA} BAR
//   ph3{stage B(u+2,0), B(u+2,1)} vmcnt(2) BAR.
// Ledger (1 gload/thread/half): prologue B00,B01,A00,A01,B10,B11=6,
// vmcnt(2) retires tile0. Steady: +2 A +2 B per tile, boundary vmcnt(2)
// retires B(u+1)x2+A(u+1)x2 exactly; tail vmcnt(0). WAR: B reads all
// before ph2-BAR; A-halves of buf d~ protected by boundary BAR (A reads
// happen in ph1 only, two barriers upstream).
// LDS layout/staging XOR involution unchanged (0 conflicts @16x16, R12).
// Pipeline: cvt, QKV, scores, cvtW, softmax, PV, LN1, FF1, FF2, LN2.
// Scratch 234,881,024 B.
// ---------------------------------------------------------------------------

typedef __attribute__((ext_vector_type(4))) float  f32x4;
typedef __attribute__((ext_vector_type(8))) short  short8;
typedef __attribute__((ext_vector_type(4))) short  short4v;
typedef __attribute__((ext_vector_type(8))) __bf16 bf16x8;
typedef unsigned short ushort_t;

static __device__ __forceinline__ unsigned short f2bf(float f) {
  unsigned u = __builtin_bit_cast(unsigned, f);
  u += 0x7fffu + ((u >> 16) & 1u);  // RNE
  return (unsigned short)(u >> 16);
}
static __device__ __forceinline__ float bf2f(unsigned short u) {
  return __builtin_bit_cast(float, (unsigned)u << 16);
}

#define GLDS16(g, l)                                                        \
  __builtin_amdgcn_global_load_lds(                                         \
      (const __attribute__((address_space(1))) void*)(g),                   \
      (__attribute__((address_space(3))) void*)(l), 16, 0, 0)

// ---------------------------------------------------------------------------
__global__ __launch_bounds__(256) void cvt_f32_bf16(
    const float* __restrict__ in, ushort_t* __restrict__ out, long n) {
  long i = ((long)blockIdx.x * 256 + threadIdx.x) * 8;
  if (i >= n) return;
  f32x4 a = *(const f32x4*)(in + i);
  f32x4 b = *(const f32x4*)(in + i + 4);
  short8 t;
  t[0] = (short)f2bf(a.x); t[1] = (short)f2bf(a.y);
  t[2] = (short)f2bf(a.z); t[3] = (short)f2bf(a.w);
  t[4] = (short)f2bf(b.x); t[5] = (short)f2bf(b.y);
  t[6] = (short)f2bf(b.z); t[7] = (short)f2bf(b.w);
  *(short8*)(out + i) = t;
}

// ---------------------------------------------------------------------------
enum { EP_QKV = 0, EP_BF16 = 1, EP_PV = 2, EP_FF1 = 3, EP_FF2 = 4 };

constexpr long BSDc = 8L * 2048 * 1024;

template <int EPI>
__global__ __launch_bounds__(1024, 1) void gemm_bt(
    const ushort_t* __restrict__ A, const ushort_t* __restrict__ B,
    void* __restrict__ C, int N, int K, long sA, long sB, long sC, long sRes,
    const float* __restrict__ bias, const float* __restrict__ res,
    float scale) {
  // [dbuf][half][128 rows x 64 k] per operand: 2*2*16KB*2 = 128KB.
  __shared__ __align__(16) ushort_t As[2][2][8192];
  __shared__ __align__(16) ushort_t Bs[2][2][8192];
  const int tid  = threadIdx.x;
  const int lane = tid & 63;
  const int w    = tid >> 6;        // 0..15
  const int wm2  = w >> 2;          // 0..3 : wave row group (64 rows)
  const int wn2  = w & 3;           // 0..3 : wave col group (64 cols)
  const int l15  = lane & 15;
  const int hi   = lane >> 4;       // 0..3 : 8-elem k-chunk
  const long bz  = blockIdx.z;
  const long m0  = (long)blockIdx.x * 256;
  const long n0  = (long)blockIdx.y * 256;
  const ushort_t* Ab = A + bz * sA;
  const ushort_t* Bb = B + bz * sB;

  // Staging source: thread handles phys chunk P = tid of each 1024-chunk
  // half. row = P>>3, slot = (P&7)^(row&7) (inverse of read-side XOR).
  const int srow = tid >> 3;
  const int sc   = (tid & 7) ^ (srow & 7);
  const long offA0 = (m0 + srow) * (long)K + sc * 8;
  const long offB0 = (n0 + srow) * (long)K + sc * 8;
  const int dst = (w << 9);  // wave-uniform base (ushorts); +lane*16B by HW

#define STAGE_A(t, h)                                                       \
  GLDS16(Ab + offA0 + (long)(t) * 64 + (long)(h) * 128 * K,                 \
         &As[(t) & 1][h][0] + dst);
#define STAGE_B(t, h)                                                       \
  GLDS16(Bb + offB0 + (long)(t) * 64 + (long)(h) * 128 * K,                 \
         &Bs[(t) & 1][h][0] + dst);

  // Read-side swizzled byte offsets (k-step 0 / 1), lane-constant.
  const int ab0 = l15 * 128 + ((hi) ^ (l15 & 7)) * 16;
  const int ab1 = l15 * 128 + ((4 + hi) ^ (l15 & 7)) * 16;

#define READ_A_ALL                                                          \
  _Pragma("unroll") for (int i = 0; i < 4; ++i) {                           \
    afr[i][0] = *(const short8*)(Ah + i * 2048 + ab0);                      \
    afr[i][1] = *(const short8*)(Ah + i * 2048 + ab1);                      \
  }
#define READ_B2(bj0)                                                        \
  _Pragma("unroll") for (int jj = 0; jj < 2; ++jj) {                        \
    bfr[jj][0] = *(const short8*)(Bh + ((bj0) + jj) * 2048 + ab0);          \
    bfr[jj][1] = *(const short8*)(Bh + ((bj0) + jj) * 2048 + ab1);          \
  }
#define QMFMA(jb)                                                           \
  _Pragma("unroll") for (int i = 0; i < 4; ++i)                             \
  _Pragma("unroll") for (int jj = 0; jj < 2; ++jj)                          \
  _Pragma("unroll") for (int ks = 0; ks < 2; ++ks)                          \
    acc[i][(jb) + jj] = __builtin_amdgcn_mfma_f32_16x16x32_bf16(            \
        __builtin_bit_cast(bf16x8, afr[i][ks]),                             \
        __builtin_bit_cast(bf16x8, bfr[jj][ks]), acc[i][(jb) + jj], 0, 0,   \
        0);

  f32x4 acc[4][4] = {};
  const int NT = K >> 6;  // K-tiles of 64 (16 or 32)

  // Prologue ring: (0).B0,B1,A0,A1,(1).B0,B1 = 6 loads; retire tile 0.
  STAGE_B(0, 0) STAGE_B(0, 1) STAGE_A(0, 0) STAGE_A(0, 1)
  STAGE_B(1, 0) STAGE_B(1, 1)
  asm volatile("s_waitcnt vmcnt(2)" ::: "memory");
  __builtin_amdgcn_sched_barrier(0);
  __builtin_amdgcn_s_barrier();
  __builtin_amdgcn_sched_barrier(0);

  for (int u = 0; u < NT; ++u) {
    const int d = u & 1;
    const char* Ah = (const char*)&As[d][wm2 >> 1][0] + (wm2 & 1) * 8192;
    const char* Bh = (const char*)&Bs[d][wn2 >> 1][0] + (wn2 & 1) * 8192;
    short8 afr[4][2], bfr[2][2];
    // ---- phase 1: A(all) x B(0,1) ----
    READ_A_ALL
    READ_B2(0)
    if (u + 1 < NT) STAGE_A(u + 1, 0)
    __builtin_amdgcn_s_setprio(1);
    QMFMA(0)
    __builtin_amdgcn_s_setprio(0);
    // ---- phase 2: A(all) x B(2,3) ----
    READ_B2(2)
    if (u + 1 < NT) STAGE_A(u + 1, 1)
    __builtin_amdgcn_s_setprio(1);
    QMFMA(2)
    __builtin_amdgcn_s_setprio(0);
    __builtin_amdgcn_s_barrier();  // all waves done reading buf d B-halves
    // ---- phase 3: stage next-next B (flies across boundary) ----
    if (u + 2 < NT) {
      STAGE_B(u + 2, 0)
      STAGE_B(u + 2, 1)
    }
    // ---- K-tile boundary: tile u+1 must be fully resident ----
    if (u + 1 < NT) {
      if (u + 2 < NT) {
        asm volatile("s_waitcnt vmcnt(2)" ::: "memory");
      } else {
        asm volatile("s_waitcnt vmcnt(0)" ::: "memory");
      }
      __builtin_amdgcn_sched_barrier(0);
      __builtin_amdgcn_s_barrier();
      __builtin_amdgcn_sched_barrier(0);
    }
  }
#undef STAGE_A
#undef STAGE_B
#undef READ_A_ALL
#undef READ_B2
#undef QMFMA

  // Epilogue. C/D layout: col = lane&15, row = (lane>>4)*4 + reg.
  const int rb0 = hi << 2;
  const int cl  = l15;
#pragma unroll
  for (int i = 0; i < 4; ++i) {
#pragma unroll
    for (int j = 0; j < 4; ++j) {
      long gmb = m0 + wm2 * 64 + i * 16 + rb0;
      long gc  = n0 + wn2 * 64 + j * 16 + cl;
      if constexpr (EPI == EP_QKV) {
        long which = gc >> 10;  // 0=q, 1=k, 2=v (uniform per block)
        long col   = gc & 1023;
        if (which == 2) {
          long bb = gmb >> 11, s = gmb & 2047;
          short4v pk;
#pragma unroll
          for (int r = 0; r < 4; ++r) pk[r] = (short)f2bf(acc[i][j][r]);
          *(short4v*)((ushort_t*)C + 2 * BSDc + ((bb << 10) + col) * 2048 + s) =
              pk;
        } else {
#pragma unroll
          for (int r = 0; r < 4; ++r)
            ((ushort_t*)C)[which * BSDc + (gmb + r) * 1024 + col] =
                f2bf(acc[i][j][r]);
        }
      } else {
#pragma unroll
        for (int r = 0; r < 4; ++r) {
          long gm = gmb + r;
          float v = acc[i][j][r] * scale;
          if constexpr (EPI == EP_BF16) {
            ((ushort_t*)C)[bz * sC + gm * N + gc] = f2bf(v);
          } else if constexpr (EPI == EP_PV) {
            v += res[bz * sRes + gm * N + gc];
            ((float*)C)[bz * sC + gm * N + gc] = v;
          } else if constexpr (EPI == EP_FF1) {
            v += bias[gc];
            v = v > 0.f ? v : 0.f;
            ((ushort_t*)C)[gm * N + gc] = f2bf(v);
          } else {  // EP_FF2
            v += bias[gc] + res[gm * N + gc];
            ((float*)C)[gm * N + gc] = v;
          }
        }
      }
    }
  }
}

// ---------------------------------------------------------------------------
__global__ __launch_bounds__(256) void softmax_inplace(
    ushort_t* __restrict__ P) {
  __shared__ float rmax[4], rsum[4];
  const int tid   = threadIdx.x;
  const long base = (long)blockIdx.x * 2048;
  short8 sv = *(const short8*)(P + base + tid * 8);
  float v[8];
#pragma unroll
  for (int j = 0; j < 8; ++j) v[j] = bf2f((unsigned short)sv[j]);
  float mx = v[0];
#pragma unroll
  for (int j = 1; j < 8; ++j) mx = fmaxf(mx, v[j]);
#pragma unroll
  for (int off = 32; off; off >>= 1) mx = fmaxf(mx, __shfl_down(mx, off, 64));
  if ((tid & 63) == 0) rmax[tid >> 6] = mx;
  __syncthreads();
  mx = fmaxf(fmaxf(rmax[0], rmax[1]), fmaxf(rmax[2], rmax[3]));
  float s = 0.f;
#pragma unroll
  for (int j = 0; j < 8; ++j) {
    v[j] = __expf(v[j] - mx);
    s += v[j];
  }
#pragma unroll
  for (int off = 32; off; off >>= 1) s += __shfl_down(s, off, 64);
  if ((tid & 63) == 0) rsum[tid >> 6] = s;
  __syncthreads();
  s = (rsum[0] + rsum[1]) + (rsum[2] + rsum[3]);
  float inv = 1.f / s;
  short8 o;
#pragma unroll
  for (int j = 0; j < 8; ++j) o[j] = (short)f2bf(v[j] * inv);
  *(short8*)(P + base + tid * 8) = o;
}

// ---------------------------------------------------------------------------
template <int MODE>
__global__ __launch_bounds__(256) void ln_row(const float* __restrict__ X,
                                              const float* __restrict__ g,
                                              const float* __restrict__ be,
                                              float* __restrict__ Yf,
                                              ushort_t* __restrict__ Yb) {
  __shared__ float rs[4], rq[4];
  const int tid   = threadIdx.x;
  const long base = (long)blockIdx.x << 10;
  f32x4 v = *(const f32x4*)(X + base + tid * 4);
  float s = v.x + v.y + v.z + v.w;
  float q = v.x * v.x + v.y * v.y + v.z * v.z + v.w * v.w;
#pragma unroll
  for (int off = 32; off; off >>= 1) {
    s += __shfl_down(s, off, 64);
    q += __shfl_down(q, off, 64);
  }
  if ((tid & 63) == 0) {
    rs[tid >> 6] = s;
    rq[tid >> 6] = q;
  }
  __syncthreads();
  s = (rs[0] + rs[1]) + (rs[2] + rs[3]);
  q = (rq[0] + rq[1]) + (rq[2] + rq[3]);
  float mu   = s * (1.f / 1024.f);
  float var  = q * (1.f / 1024.f) - mu * mu;
  float rstd = rsqrtf(var + 1e-5f);
  int c    = tid * 4;
  f32x4 gg = *(const f32x4*)(g + c);
  f32x4 bb = *(const f32x4*)(be + c);
  f32x4 y;
  y.x = (v.x - mu) * rstd * gg.x + bb.x;
  y.y = (v.y - mu) * rstd * gg.y + bb.y;
  y.z = (v.z - mu) * rstd * gg.z + bb.z;
  y.w = (v.w - mu) * rstd * gg.w + bb.w;
  *(f32x4*)(Yf + base + c) = y;
  if constexpr (MODE == 0) {
    short4v ob;
    ob[0] = (short)f2bf(y.x);
    ob[1] = (short)f2bf(y.y);
    ob[2] = (short)f2bf(y.z);
    ob[3] = (short)f2bf(y.w);
    *(short4v*)(Yb + base + c) = ob;
  }
}

// ---------------------------------------------------------------------------
extern "C" void kernel_launch(void* const* d_in, const int* in_sizes, int n_in,
                              void* d_out, int out_size, void* d_ws,
                              size_t ws_size, hipStream_t stream) {
  const float* x   = (const float*)d_in[0];
  const float* Wq  = (const float*)d_in[1];
  const float* Wk  = (const float*)d_in[2];
  const float* Wv  = (const float*)d_in[3];
  const float* W1  = (const float*)d_in[4];
  const float* b1  = (const float*)d_in[5];
  const float* W2  = (const float*)d_in[6];
  const float* b2  = (const float*)d_in[7];
  const float* g1  = (const float*)d_in[8];
  const float* be1 = (const float*)d_in[9];
  const float* g2  = (const float*)d_in[10];
  const float* be2 = (const float*)d_in[11];
  float* out = (float*)d_out;

  constexpr long BSD = 8L * 2048 * 1024;
  constexpr long BSS = 8L * 2048 * 2048;
  constexpr long DD  = 1024L * 1024;
  constexpr long HD  = 2048L * 1024;

  // Scratch: qb | kb | vTb | sP | r1  = 234,881,024 bytes total.
  ushort_t* qb  = (ushort_t*)d_ws;
  ushort_t* kb  = qb + BSD;
  ushort_t* vTb = kb + BSD;
  ushort_t* sP  = vTb + BSD;
  float*    r1  = (float*)(sP + BSS);

  ushort_t* xb    = sP;              // dead before scores written
  ushort_t* Wqkvb = (ushort_t*)r1;   // dead before PV writes r1
  ushort_t* W1b   = kb;              // converted after scores GEMM
  ushort_t* W2b   = kb + HD;
  ushort_t* hb    = qb;
  float*    h     = out;             // d_out dead until LN2 rewrites it

  dim3 blk(256), gblk(1024);
  const long SD = 2048L * 1024, SS = 2048L * 2048, DS = 1024L * 2048;

  // 0: conversions
  cvt_f32_bf16<<<dim3(8192), blk, 0, stream>>>(x, xb, BSD);
  cvt_f32_bf16<<<dim3(512), blk, 0, stream>>>(Wq, Wqkvb, DD);
  cvt_f32_bf16<<<dim3(512), blk, 0, stream>>>(Wk, Wqkvb + DD, DD);
  cvt_f32_bf16<<<dim3(512), blk, 0, stream>>>(Wv, Wqkvb + 2 * DD, DD);
  // 1: fused QKV projection (M=16384, N=3072, K=1024)
  gemm_bt<EP_QKV><<<dim3(64, 12, 1), gblk, 0, stream>>>(
      xb, Wqkvb, qb, 3072, 1024, 0, 0, 0, 0, nullptr, nullptr, 1.f);
  // 2: scores = q@k^T / 32 (per batch: M=N=2048, K=1024)
  gemm_bt<EP_BF16><<<dim3(8, 8, 8), gblk, 0, stream>>>(
      qb, kb, sP, 2048, 1024, SD, SD, SS, 0, nullptr, nullptr, 0.03125f);
  // 2b: FFN weights into kb region (kb dead now)
  cvt_f32_bf16<<<dim3(1024), blk, 0, stream>>>(W1, W1b, HD);
  cvt_f32_bf16<<<dim3(1024), blk, 0, stream>>>(W2, W2b, HD);
  // 3: softmax
  softmax_inplace<<<dim3(16384), blk, 0, stream>>>(sP);
  // 4: attn_out + x (per batch: M=2048, N=1024, K=2048)
  gemm_bt<EP_PV><<<dim3(8, 4, 8), gblk, 0, stream>>>(
      sP, vTb, r1, 1024, 2048, SS, DS, SD, SD, nullptr, x, 1.f);
  // 5: LN1 -> h (fp32, in d_out) + hb (bf16, aliases qb)
  ln_row<0><<<dim3(16384), blk, 0, stream>>>(r1, g1, be1, h, hb);
  // 6: ff1 = relu(hb@W1^T + b1) (M=16384, N=2048, K=1024)
  gemm_bt<EP_FF1><<<dim3(64, 8, 1), gblk, 0, stream>>>(
      hb, W1b, sP, 2048, 1024, 0, 0, 0, 0, b1, nullptr, 1.f);
  // 7: res2 = ff1@W2^T + b2 + h (M=16384, N=1024, K=2048)
  gemm_bt<EP_FF2><<<dim3(64, 4, 1), gblk, 0, stream>>>(
      sP, W2b, r1, 1024, 2048, 0, 0, 0, 0, b2, h, 1.f);
  // 8: LN2 -> out (overwrites h)
  ln_row<1><<<dim3(16384), blk, 0, stream>>>(r1, g2, be2, out, nullptr);
}

// Round 15
// 493.326 us; speedup vs baseline: 1.2441x; 1.2441x over previous
//
#include <hip/hip_runtime.h>
#include <hip/hip_bf16.h>

// ---------------------------------------------------------------------------
// MiniTransformer: B=8,S=2048,D=1024,H=2048, fp32 in/out, bf16 MFMA inside.
// GEMM: R12 ring (best, 494us): 256x256 tile, BK=64, 8 waves (2Mx4N),
// 2-dbuf LDS (128KB), 4 phases/K-tile, 2 barriers/K-tile (post-ph2 +
// boundary), counted vmcnt(4) ledger (never 0 in steady state),
// compiler-counted lgkm waits (no forced drains).
// R15 change (single variable vs R12): REMOVED s_setprio brackets. T5 is
// null on non-phase-locked structures (m190) and the intrinsic's unmodeled
// side effects likely fence the scheduler, blocking cross-phase hoisting of
// ph2/ph3 ds_reads over the previous MFMA cluster. Correctness unaffected
// (setprio orders nothing; s_barrier still fences staging writes).
// R13 (32x32 MFMA) and R14 (16 waves) both regressed and are reverted.
// LDS layout per half [128 rows][64k], slot XOR involution, 0 conflicts.
// Pipeline: cvt, QKV, scores, cvtW, softmax, PV, LN1, FF1, FF2, LN2.
// Scratch 234,881,024 B.
// ---------------------------------------------------------------------------

typedef __attribute__((ext_vector_type(4))) float  f32x4;
typedef __attribute__((ext_vector_type(8))) short  short8;
typedef __attribute__((ext_vector_type(4))) short  short4v;
typedef __attribute__((ext_vector_type(8))) __bf16 bf16x8;
typedef unsigned short ushort_t;

static __device__ __forceinline__ unsigned short f2bf(float f) {
  unsigned u = __builtin_bit_cast(unsigned, f);
  u += 0x7fffu + ((u >> 16) & 1u);  // RNE
  return (unsigned short)(u >> 16);
}
static __device__ __forceinline__ float bf2f(unsigned short u) {
  return __builtin_bit_cast(float, (unsigned)u << 16);
}

#define GLDS16(g, l)                                                        \
  __builtin_amdgcn_global_load_lds(                                         \
      (const __attribute__((address_space(1))) void*)(g),                   \
      (__attribute__((address_space(3))) void*)(l), 16, 0, 0)

// ---------------------------------------------------------------------------
__global__ __launch_bounds__(256) void cvt_f32_bf16(
    const float* __restrict__ in, ushort_t* __restrict__ out, long n) {
  long i = ((long)blockIdx.x * 256 + threadIdx.x) * 8;
  if (i >= n) return;
  f32x4 a = *(const f32x4*)(in + i);
  f32x4 b = *(const f32x4*)(in + i + 4);
  short8 t;
  t[0] = (short)f2bf(a.x); t[1] = (short)f2bf(a.y);
  t[2] = (short)f2bf(a.z); t[3] = (short)f2bf(a.w);
  t[4] = (short)f2bf(b.x); t[5] = (short)f2bf(b.y);
  t[6] = (short)f2bf(b.z); t[7] = (short)f2bf(b.w);
  *(short8*)(out + i) = t;
}

// ---------------------------------------------------------------------------
enum { EP_QKV = 0, EP_BF16 = 1, EP_PV = 2, EP_FF1 = 3, EP_FF2 = 4 };

constexpr long BSDc = 8L * 2048 * 1024;

template <int EPI>
__global__ __launch_bounds__(512, 2) void gemm_bt(
    const ushort_t* __restrict__ A, const ushort_t* __restrict__ B,
    void* __restrict__ C, int N, int K, long sA, long sB, long sC, long sRes,
    const float* __restrict__ bias, const float* __restrict__ res,
    float scale) {
  // [dbuf][half][128 rows x 64 k] per operand: 2*2*16KB*2 = 128KB.
  __shared__ __align__(16) ushort_t As[2][2][8192];
  __shared__ __align__(16) ushort_t Bs[2][2][8192];
  const int tid  = threadIdx.x;
  const int lane = tid & 63;
  const int w    = tid >> 6;        // 0..7
  const int wm   = w >> 2;          // 0..1 : wave row-half (128 rows)
  const int wn   = w & 3;           // 0..3 : wave col (64 cols)
  const int l15  = lane & 15;
  const int hi   = lane >> 4;       // 0..3 : 8-elem k-chunk
  const long bz  = blockIdx.z;
  const long m0  = (long)blockIdx.x * 256;
  const long n0  = (long)blockIdx.y * 256;
  const ushort_t* Ab = A + bz * sA;
  const ushort_t* Bb = B + bz * sB;

  // Staging source (inverse of read-side XOR): thread handles phys chunks
  // tid and tid+512 of each 1024-chunk half. row = P>>3, slot = (P&7)^(row&7).
  const int srow = tid >> 3;
  const int sc   = (tid & 7) ^ (srow & 7);
  const long offA0 = (m0 + srow) * (long)K + sc * 8;
  const long offB0 = (n0 + srow) * (long)K + sc * 8;
  const int dst0 = w * 512;
  const int dst1 = 4096 + w * 512;

#define STAGE_A(t, h)                                                       \
  {                                                                         \
    const long o_ = (long)(t) * 64 + (long)(h) * 128 * K;                   \
    ushort_t* l_ = &As[(t) & 1][h][0];                                      \
    GLDS16(Ab + offA0 + o_, l_ + dst0);                                     \
    GLDS16(Ab + offA0 + 64 * (long)K + o_, l_ + dst1);                      \
  }
#define STAGE_B(t, h)                                                       \
  {                                                                         \
    const long o_ = (long)(t) * 64 + (long)(h) * 128 * K;                   \
    ushort_t* l_ = &Bs[(t) & 1][h][0];                                      \
    GLDS16(Bb + offB0 + o_, l_ + dst0);                                     \
    GLDS16(Bb + offB0 + 64 * (long)K + o_, l_ + dst1);                      \
  }

  // Read-side swizzled byte offsets (k-step 0 / 1), lane-constant.
  const int ab0 = l15 * 128 + ((hi) ^ (l15 & 7)) * 16;
  const int ab1 = l15 * 128 + ((4 + hi) ^ (l15 & 7)) * 16;

#define READ_A(ai)                                                          \
  _Pragma("unroll") for (int i = 0; i < 4; ++i) {                           \
    afr[i][0] = *(const short8*)(Ah + (ai) * 8192 + i * 2048 + ab0);        \
    afr[i][1] = *(const short8*)(Ah + (ai) * 8192 + i * 2048 + ab1);        \
  }
#define READ_B(bj)                                                          \
  _Pragma("unroll") for (int j = 0; j < 2; ++j) {                           \
    bfr[bj][j][0] = *(const short8*)(Bh + (bj) * 4096 + j * 2048 + ab0);    \
    bfr[bj][j][1] = *(const short8*)(Bh + (bj) * 4096 + j * 2048 + ab1);    \
  }
#define QMFMA(ib, jb, bsel)                                                 \
  _Pragma("unroll") for (int i = 0; i < 4; ++i)                             \
  _Pragma("unroll") for (int j = 0; j < 2; ++j)                             \
  _Pragma("unroll") for (int ks = 0; ks < 2; ++ks)                          \
    acc[(ib) + i][(jb) + j] = __builtin_amdgcn_mfma_f32_16x16x32_bf16(      \
        __builtin_bit_cast(bf16x8, afr[i][ks]),                             \
        __builtin_bit_cast(bf16x8, bfr[bsel][j][ks]),                       \
        acc[(ib) + i][(jb) + j], 0, 0, 0);

  f32x4 acc[8][4] = {};
  const int NT = K >> 6;  // K-tiles of 64 (16 or 32)

  // Prologue ring: (0).B0,B1,A0,A1,(1).B0,B1 = 12 loads; retire tile 0.
  STAGE_B(0, 0) STAGE_B(0, 1) STAGE_A(0, 0) STAGE_A(0, 1)
  STAGE_B(1, 0) STAGE_B(1, 1)
  asm volatile("s_waitcnt vmcnt(4)" ::: "memory");
  __builtin_amdgcn_sched_barrier(0);
  __builtin_amdgcn_s_barrier();
  __builtin_amdgcn_sched_barrier(0);

  for (int u = 0; u < NT; ++u) {
    const int d = u & 1;
    const char* Ah = (const char*)&As[d][wm][0];
    const char* Bh = (const char*)&Bs[d][wn >> 1][0] + (wn & 1) * 8192;
    short8 afr[4][2], bfr[2][2][2];
    // ---- phase 1: quadrant A0 x B0 (no bars: buf d confirmed at entry) ----
    READ_A(0)
    READ_B(0)
    if (u + 1 < NT) STAGE_A(u + 1, 0)
    QMFMA(0, 0, 0)
    // ---- phase 2: quadrant A0 x B1 ----
    READ_B(1)
    if (u + 1 < NT) STAGE_A(u + 1, 1)
    QMFMA(0, 2, 1)
    __builtin_amdgcn_s_barrier();  // all waves done reading B-halves of buf d
    // ---- phase 3: quadrant A1 x B1 (stage may overwrite buf d B0 now) ----
    READ_A(1)
    if (u + 2 < NT) STAGE_B(u + 2, 0)
    QMFMA(4, 2, 1)
    // ---- phase 4: quadrant A1 x B0 (all from regs) ----
    if (u + 2 < NT) STAGE_B(u + 2, 1)
    QMFMA(4, 0, 0)
    // ---- K-tile boundary: tile u+1 must be fully resident ----
    if (u + 1 < NT) {
      if (u + 2 < NT) {
        asm volatile("s_waitcnt vmcnt(4)" ::: "memory");
      } else {
        asm volatile("s_waitcnt vmcnt(0)" ::: "memory");
      }
      __builtin_amdgcn_sched_barrier(0);
      __builtin_amdgcn_s_barrier();
      __builtin_amdgcn_sched_barrier(0);
    }
  }
#undef STAGE_A
#undef STAGE_B
#undef READ_A
#undef READ_B
#undef QMFMA

  // Epilogue. C/D layout: col = lane&15, row = (lane>>4)*4 + reg.
  const int rb0 = hi << 2;
  const int cl  = l15;
#pragma unroll
  for (int i = 0; i < 8; ++i) {
#pragma unroll
    for (int j = 0; j < 4; ++j) {
      long gmb = m0 + wm * 128 + i * 16 + rb0;
      long gc  = n0 + wn * 64 + j * 16 + cl;
      if constexpr (EPI == EP_QKV) {
        long which = gc >> 10;  // 0=q, 1=k, 2=v (uniform per block)
        long col   = gc & 1023;
        if (which == 2) {
          long bb = gmb >> 11, s = gmb & 2047;
          short4v pk;
#pragma unroll
          for (int r = 0; r < 4; ++r) pk[r] = (short)f2bf(acc[i][j][r]);
          *(short4v*)((ushort_t*)C + 2 * BSDc + ((bb << 10) + col) * 2048 + s) =
              pk;
        } else {
#pragma unroll
          for (int r = 0; r < 4; ++r)
            ((ushort_t*)C)[which * BSDc + (gmb + r) * 1024 + col] =
                f2bf(acc[i][j][r]);
        }
      } else {
#pragma unroll
        for (int r = 0; r < 4; ++r) {
          long gm = gmb + r;
          float v = acc[i][j][r] * scale;
          if constexpr (EPI == EP_BF16) {
            ((ushort_t*)C)[bz * sC + gm * N + gc] = f2bf(v);
          } else if constexpr (EPI == EP_PV) {
            v += res[bz * sRes + gm * N + gc];
            ((float*)C)[bz * sC + gm * N + gc] = v;
          } else if constexpr (EPI == EP_FF1) {
            v += bias[gc];
            v = v > 0.f ? v : 0.f;
            ((ushort_t*)C)[gm * N + gc] = f2bf(v);
          } else {  // EP_FF2
            v += bias[gc] + res[gm * N + gc];
            ((float*)C)[gm * N + gc] = v;
          }
        }
      }
    }
  }
}

// ---------------------------------------------------------------------------
__global__ __launch_bounds__(256) void softmax_inplace(
    ushort_t* __restrict__ P) {
  __shared__ float rmax[4], rsum[4];
  const int tid   = threadIdx.x;
  const long base = (long)blockIdx.x * 2048;
  short8 sv = *(const short8*)(P + base + tid * 8);
  float v[8];
#pragma unroll
  for (int j = 0; j < 8; ++j) v[j] = bf2f((unsigned short)sv[j]);
  float mx = v[0];
#pragma unroll
  for (int j = 1; j < 8; ++j) mx = fmaxf(mx, v[j]);
#pragma unroll
  for (int off = 32; off; off >>= 1) mx = fmaxf(mx, __shfl_down(mx, off, 64));
  if ((tid & 63) == 0) rmax[tid >> 6] = mx;
  __syncthreads();
  mx = fmaxf(fmaxf(rmax[0], rmax[1]), fmaxf(rmax[2], rmax[3]));
  float s = 0.f;
#pragma unroll
  for (int j = 0; j < 8; ++j) {
    v[j] = __expf(v[j] - mx);
    s += v[j];
  }
#pragma unroll
  for (int off = 32; off; off >>= 1) s += __shfl_down(s, off, 64);
  if ((tid & 63) == 0) rsum[tid >> 6] = s;
  __syncthreads();
  s = (rsum[0] + rsum[1]) + (rsum[2] + rsum[3]);
  float inv = 1.f / s;
  short8 o;
#pragma unroll
  for (int j = 0; j < 8; ++j) o[j] = (short)f2bf(v[j] * inv);
  *(short8*)(P + base + tid * 8) = o;
}

// ---------------------------------------------------------------------------
template <int MODE>
__global__ __launch_bounds__(256) void ln_row(const float* __restrict__ X,
                                              const float* __restrict__ g,
                                              const float* __restrict__ be,
                                              float* __restrict__ Yf,
                                              ushort_t* __restrict__ Yb) {
  __shared__ float rs[4], rq[4];
  const int tid   = threadIdx.x;
  const long base = (long)blockIdx.x << 10;
  f32x4 v = *(const f32x4*)(X + base + tid * 4);
  float s = v.x + v.y + v.z + v.w;
  float q = v.x * v.x + v.y * v.y + v.z * v.z + v.w * v.w;
#pragma unroll
  for (int off = 32; off; off >>= 1) {
    s += __shfl_down(s, off, 64);
    q += __shfl_down(q, off, 64);
  }
  if ((tid & 63) == 0) {
    rs[tid >> 6] = s;
    rq[tid >> 6] = q;
  }
  __syncthreads();
  s = (rs[0] + rs[1]) + (rs[2] + rs[3]);
  q = (rq[0] + rq[1]) + (rq[2] + rq[3]);
  float mu   = s * (1.f / 1024.f);
  float var  = q * (1.f / 1024.f) - mu * mu;
  float rstd = rsqrtf(var + 1e-5f);
  int c    = tid * 4;
  f32x4 gg = *(const f32x4*)(g + c);
  f32x4 bb = *(const f32x4*)(be + c);
  f32x4 y;
  y.x = (v.x - mu) * rstd * gg.x + bb.x;
  y.y = (v.y - mu) * rstd * gg.y + bb.y;
  y.z = (v.z - mu) * rstd * gg.z + bb.z;
  y.w = (v.w - mu) * rstd * gg.w + bb.w;
  *(f32x4*)(Yf + base + c) = y;
  if constexpr (MODE == 0) {
    short4v ob;
    ob[0] = (short)f2bf(y.x);
    ob[1] = (short)f2bf(y.y);
    ob[2] = (short)f2bf(y.z);
    ob[3] = (short)f2bf(y.w);
    *(short4v*)(Yb + base + c) = ob;
  }
}

// ---------------------------------------------------------------------------
extern "C" void kernel_launch(void* const* d_in, const int* in_sizes, int n_in,
                              void* d_out, int out_size, void* d_ws,
                              size_t ws_size, hipStream_t stream) {
  const float* x   = (const float*)d_in[0];
  const float* Wq  = (const float*)d_in[1];
  const float* Wk  = (const float*)d_in[2];
  const float* Wv  = (const float*)d_in[3];
  const float* W1  = (const float*)d_in[4];
  const float* b1  = (const float*)d_in[5];
  const float* W2  = (const float*)d_in[6];
  const float* b2  = (const float*)d_in[7];
  const float* g1  = (const float*)d_in[8];
  const float* be1 = (const float*)d_in[9];
  const float* g2  = (const float*)d_in[10];
  const float* be2 = (const float*)d_in[11];
  float* out = (float*)d_out;

  constexpr long BSD = 8L * 2048 * 1024;
  constexpr long BSS = 8L * 2048 * 2048;
  constexpr long DD  = 1024L * 1024;
  constexpr long HD  = 2048L * 1024;

  // Scratch: qb | kb | vTb | sP | r1  = 234,881,024 bytes total.
  ushort_t* qb  = (ushort_t*)d_ws;
  ushort_t* kb  = qb + BSD;
  ushort_t* vTb = kb + BSD;
  ushort_t* sP  = vTb + BSD;
  float*    r1  = (float*)(sP + BSS);

  ushort_t* xb    = sP;              // dead before scores written
  ushort_t* Wqkvb = (ushort_t*)r1;   // dead before PV writes r1
  ushort_t* W1b   = kb;              // converted after scores GEMM
  ushort_t* W2b   = kb + HD;
  ushort_t* hb    = qb;
  float*    h     = out;             // d_out dead until LN2 rewrites it

  dim3 blk(256), gblk(512);
  const long SD = 2048L * 1024, SS = 2048L * 2048, DS = 1024L * 2048;

  // 0: conversions
  cvt_f32_bf16<<<dim3(8192), blk, 0, stream>>>(x, xb, BSD);
  cvt_f32_bf16<<<dim3(512), blk, 0, stream>>>(Wq, Wqkvb, DD);
  cvt_f32_bf16<<<dim3(512), blk, 0, stream>>>(Wk, Wqkvb + DD, DD);
  cvt_f32_bf16<<<dim3(512), blk, 0, stream>>>(Wv, Wqkvb + 2 * DD, DD);
  // 1: fused QKV projection (M=16384, N=3072, K=1024)
  gemm_bt<EP_QKV><<<dim3(64, 12, 1), gblk, 0, stream>>>(
      xb, Wqkvb, qb, 3072, 1024, 0, 0, 0, 0, nullptr, nullptr, 1.f);
  // 2: scores = q@k^T / 32 (per batch: M=N=2048, K=1024)
  gemm_bt<EP_BF16><<<dim3(8, 8, 8), gblk, 0, stream>>>(
      qb, kb, sP, 2048, 1024, SD, SD, SS, 0, nullptr, nullptr, 0.03125f);
  // 2b: FFN weights into kb region (kb dead now)
  cvt_f32_bf16<<<dim3(1024), blk, 0, stream>>>(W1, W1b, HD);
  cvt_f32_bf16<<<dim3(1024), blk, 0, stream>>>(W2, W2b, HD);
  // 3: softmax
  softmax_inplace<<<dim3(16384), blk, 0, stream>>>(sP);
  // 4: attn_out + x (per batch: M=2048, N=1024, K=2048)
  gemm_bt<EP_PV><<<dim3(8, 4, 8), gblk, 0, stream>>>(
      sP, vTb, r1, 1024, 2048, SS, DS, SD, SD, nullptr, x, 1.f);
  // 5: LN1 -> h (fp32, in d_out) + hb (bf16, aliases qb)
  ln_row<0><<<dim3(16384), blk, 0, stream>>>(r1, g1, be1, h, hb);
  // 6: ff1 = relu(hb@W1^T + b1) (M=16384, N=2048, K=1024)
  gemm_bt<EP_FF1><<<dim3(64, 8, 1), gblk, 0, stream>>>(
      hb, W1b, sP, 2048, 1024, 0, 0, 0, 0, b1, nullptr, 1.f);
  // 7: res2 = ff1@W2^T + b2 + h (M=16384, N=1024, K=2048)
  gemm_bt<EP_FF2><<<dim3(64, 4, 1), gblk, 0, stream>>>(
      sP, W2b, r1, 1024, 2048, 0, 0, 0, 0, b2, h, 1.f);
  // 8: LN2 -> out (overwrites h)
  ln_row<1><<<dim3(16384), blk, 0, stream>>>(r1, g2, be2, out, nullptr);
}